// Round 1
// baseline (887.303 us; speedup 1.0000x reference)
//
#include <hip/hip_runtime.h>
#include <cstdint>
#include <cstddef>

#define N_TOK 4096   // 2*2048 tokens
#define DM 1024      // d_model
#define FH 4096      // ffn hidden
#define NE 8         // experts
#define NSLOT (N_TOK * 2)

typedef __attribute__((ext_vector_type(8))) short short8;  // 8 bf16
typedef __attribute__((ext_vector_type(4))) float f32x4;

__device__ __forceinline__ unsigned short f2bf(float f) {
  unsigned u = __float_as_uint(f);
  u += 0x7fffu + ((u >> 16) & 1u);   // RNE
  return (unsigned short)(u >> 16);
}

// ---------------- fp32 -> bf16 conversion (memory-bound, vectorized) ----------------
__global__ void cvt_kernel(const float* __restrict__ src, unsigned short* __restrict__ dst, int n4) {
  int stride = gridDim.x * blockDim.x;
  for (int i = blockIdx.x * blockDim.x + threadIdx.x; i < n4; i += stride) {
    float4 v = reinterpret_cast<const float4*>(src)[i];
    ushort4 o;
    o.x = f2bf(v.x); o.y = f2bf(v.y); o.z = f2bf(v.z); o.w = f2bf(v.w);
    reinterpret_cast<ushort4*>(dst)[i] = o;
  }
}

// ---------------- router: logits, softmax, top-2, bucket tokens per expert ----------------
__global__ void router_kernel(const float* __restrict__ x, const float* __restrict__ Wr,
                              int* __restrict__ counts, float* __restrict__ psum,
                              int* __restrict__ lists, float* __restrict__ pslot) {
  int lane = threadIdx.x & 63;
  int token = (blockIdx.x * blockDim.x + threadIdx.x) >> 6;  // one wave per token
  if (token >= N_TOK) return;
  const float* xr = x + (size_t)token * DM;
  float acc[NE];
#pragma unroll
  for (int e = 0; e < NE; e++) acc[e] = 0.f;
  for (int d = lane; d < DM; d += 64) {
    float xv = xr[d];
#pragma unroll
    for (int e = 0; e < NE; e++) acc[e] += xv * Wr[e * DM + d];
  }
#pragma unroll
  for (int e = 0; e < NE; e++) {
#pragma unroll
    for (int off = 32; off > 0; off >>= 1) acc[e] += __shfl_xor(acc[e], off);
  }
  if (lane == 0) {
    float m = acc[0];
#pragma unroll
    for (int e = 1; e < NE; e++) m = fmaxf(m, acc[e]);
    float p[NE];
    float s = 0.f;
#pragma unroll
    for (int e = 0; e < NE; e++) { p[e] = expf(acc[e] - m); s += p[e]; }
    float inv = 1.f / s;
#pragma unroll
    for (int e = 0; e < NE; e++) p[e] *= inv;
    // top-2, earliest index wins ties (jax top_k semantics)
    int i1 = 0;
#pragma unroll
    for (int e = 1; e < NE; e++) if (p[e] > p[i1]) i1 = e;
    int i2 = (i1 == 0) ? 1 : 0;
#pragma unroll
    for (int e = 0; e < NE; e++) if (e != i1 && p[e] > p[i2]) i2 = e;
    float denom = p[i1] + p[i2] + 1e-8f;
    int pos1 = atomicAdd(&counts[i1], 1);
    lists[i1 * N_TOK + pos1] = 2 * token;
    int pos2 = atomicAdd(&counts[i2], 1);
    lists[i2 * N_TOK + pos2] = 2 * token + 1;
    pslot[2 * token]     = p[i1] / denom;
    pslot[2 * token + 1] = p[i2] / denom;
#pragma unroll
    for (int e = 0; e < NE; e++) atomicAdd(&psum[e], p[e]);
  }
}

// ---------------- aux loss ----------------
__global__ void aux_kernel(const float* __restrict__ psum, float* __restrict__ aux_out) {
  if (threadIdx.x == 0 && blockIdx.x == 0) {
    float a = 0.f;
#pragma unroll
    for (int e = 0; e < NE; e++) {
      float tpe = psum[e] * (1.0f / N_TOK);
      float d = tpe - 1.0f / NE;
      a += d * d;
    }
    aux_out[0] = 0.01f * (a * (1.0f / NE));
  }
}

// ---------------- grouped GEMM: C = gather(A) * B^T, 128x128 tile, BK=64 ----------------
// IS_GEMM1: A row = slot>>1 (token) into xb[4096][1024]; epilogue = gelu -> hb (bf16)
// else:     A row = slot into hb[8192][4096];           epilogue = p * acc -> atomicAdd out
template <int KDIM, bool IS_GEMM1>
__global__ __launch_bounds__(256) void moe_gemm(
    const unsigned short* __restrict__ Aglob,
    const unsigned short* __restrict__ Bglob,
    const int* __restrict__ counts,
    const int* __restrict__ lists,
    const float* __restrict__ pslot,
    unsigned short* __restrict__ hb,
    float* __restrict__ out) {
  int e = blockIdx.z, mt = blockIdx.y, nt = blockIdx.x;
  int cnt = counts[e];
  if (mt * 128 >= cnt) return;
  const int* list = lists + e * N_TOK;
  int Ncols = gridDim.x * 128;
  const unsigned short* B = Bglob + (size_t)e * Ncols * KDIM;

  __shared__ unsigned short As[128 * 64];
  __shared__ unsigned short Bs[128 * 64];

  int tid = threadIdx.x;
  int wid = tid >> 6;
  int lane = tid & 63;
  int wr = wid >> 1, wc = wid & 1;  // 2x2 waves, each 64x64 output

  // staging sources: 16 chunks of 1KB LDS (8 rows x 128B); wave w owns chunks i*4+w
  int acol = (lane & 7) * 8;  // bf16 col offset within BK=64
  const unsigned short* asrc[4];
  const unsigned short* bsrc[4];
#pragma unroll
  for (int i = 0; i < 4; i++) {
    int c = i * 4 + wid;
    int r = c * 8 + (lane >> 3);  // tile row 0..127
    int p = mt * 128 + r;
    int pc = p < cnt ? p : cnt - 1;
    int slot = list[pc];
    int arow = IS_GEMM1 ? (slot >> 1) : slot;
    asrc[i] = Aglob + (size_t)arow * KDIM + acol;
    bsrc[i] = B + (size_t)(nt * 128 + r) * KDIM + acol;
  }

  f32x4 acc[4][4];
#pragma unroll
  for (int m = 0; m < 4; m++)
#pragma unroll
    for (int n = 0; n < 4; n++) acc[m][n] = (f32x4){0.f, 0.f, 0.f, 0.f};

  for (int kk = 0; kk < KDIM; kk += 64) {
    if (kk > 0) __syncthreads();  // previous compute done before LDS overwrite
#pragma unroll
    for (int i = 0; i < 4; i++) {
      int c = i * 4 + wid;
      __builtin_amdgcn_global_load_lds((const void*)(asrc[i] + kk), (void*)(&As[c * 512]), 16, 0, 0);
      __builtin_amdgcn_global_load_lds((const void*)(bsrc[i] + kk), (void*)(&Bs[c * 512]), 16, 0, 0);
    }
    asm volatile("s_waitcnt vmcnt(0)" ::: "memory");
    __syncthreads();
#pragma unroll
    for (int ks = 0; ks < 2; ks++) {
      short8 a[4], b[4];
#pragma unroll
      for (int m = 0; m < 4; m++)
        a[m] = *reinterpret_cast<const short8*>(&As[(wr * 64 + m * 16 + (lane & 15)) * 64 + ks * 32 + (lane >> 4) * 8]);
#pragma unroll
      for (int n = 0; n < 4; n++)
        b[n] = *reinterpret_cast<const short8*>(&Bs[(wc * 64 + n * 16 + (lane & 15)) * 64 + ks * 32 + (lane >> 4) * 8]);
#pragma unroll
      for (int m = 0; m < 4; m++)
#pragma unroll
        for (int n = 0; n < 4; n++)
          acc[m][n] = __builtin_amdgcn_mfma_f32_16x16x32_bf16(a[m], b[n], acc[m][n], 0, 0, 0);
    }
  }

  // epilogue: C/D layout col = lane&15, row = (lane>>4)*4 + reg
  int colbase = nt * 128 + wc * 64 + (lane & 15);
#pragma unroll
  for (int m = 0; m < 4; m++) {
#pragma unroll
    for (int r = 0; r < 4; r++) {
      int row_local = wr * 64 + m * 16 + (lane >> 4) * 4 + r;
      int p = mt * 128 + row_local;
      if (p < cnt) {
        int slot = list[p];
        if (IS_GEMM1) {
          size_t base = (size_t)slot * FH + colbase;
#pragma unroll
          for (int n = 0; n < 4; n++) {
            float v = acc[m][n][r];
            float g = 0.5f * v * (1.f + erff(v * 0.70710678118654752f));
            hb[base + n * 16] = f2bf(g);
          }
        } else {
          float sc = pslot[slot];
          int token = slot >> 1;
          size_t base = (size_t)token * DM + colbase;
#pragma unroll
          for (int n = 0; n < 4; n++) atomicAdd(&out[base + n * 16], sc * acc[m][n][r]);
        }
      }
    }
  }
}

extern "C" void kernel_launch(void* const* d_in, const int* in_sizes, int n_in,
                              void* d_out, int out_size, void* d_ws, size_t ws_size,
                              hipStream_t stream) {
  const float* x  = (const float*)d_in[0];
  const float* Wr = (const float*)d_in[1];
  const float* W1 = (const float*)d_in[2];
  const float* W2 = (const float*)d_in[3];
  float* out = (float*)d_out;

  char* ws = (char*)d_ws;
  // layout (bytes)
  int*   counts = (int*)(ws + 0);                       // 32 B
  float* psum   = (float*)(ws + 32);                    // 32 B
  int*   lists  = (int*)(ws + 256);                     // 8*4096*4 = 131072
  float* pslot  = (float*)(ws + 256 + 131072);          // 8192*4 = 32768 -> ends 164096
  unsigned short* xb  = (unsigned short*)(ws + 164096);                  // 8 MiB
  unsigned short* w1b = (unsigned short*)(ws + 164096 + 8388608);        // 64 MiB
  unsigned short* w2b = (unsigned short*)(ws + 164096 + 8388608 + 67108864);
  unsigned short* hb  = (unsigned short*)(ws + 164096 + 8388608 + 2 * 67108864);
  (void)in_sizes; (void)n_in; (void)ws_size;

  hipMemsetAsync(counts, 0, 64, stream);                       // counts + psum
  hipMemsetAsync(d_out, 0, (size_t)out_size * sizeof(float), stream);

  cvt_kernel<<<2048, 256, 0, stream>>>(x,  xb,  N_TOK * DM / 4);
  cvt_kernel<<<2048, 256, 0, stream>>>(W1, w1b, NE * FH * DM / 4);
  cvt_kernel<<<2048, 256, 0, stream>>>(W2, w2b, NE * DM * FH / 4);

  router_kernel<<<N_TOK / 4, 256, 0, stream>>>(x, Wr, counts, psum, lists, pslot);
  aux_kernel<<<1, 64, 0, stream>>>(psum, out + (size_t)N_TOK * DM);

  // GEMM1: M<=cnt, N=FH(4096), K=DM(1024)
  moe_gemm<DM, true><<<dim3(FH / 128, N_TOK / 128, NE), 256, 0, stream>>>(
      xb, w1b, counts, lists, pslot, hb, nullptr);
  // GEMM2: M<=cnt, N=DM(1024), K=FH(4096)
  moe_gemm<FH, false><<<dim3(DM / 128, N_TOK / 128, NE), 256, 0, stream>>>(
      hb, w2b, counts, lists, pslot, nullptr, out);
}

// Round 2
// 399.116 us; speedup vs baseline: 2.2232x; 2.2232x over previous
//
#include <hip/hip_runtime.h>
#include <cstdint>
#include <cstddef>

#define N_TOK 4096   // 2*2048 tokens
#define DM 1024      // d_model
#define FH 4096      // ffn hidden
#define NE 8         // experts

typedef __attribute__((ext_vector_type(8))) short short8;  // 8 bf16
typedef __attribute__((ext_vector_type(4))) float f32x4;

__device__ __forceinline__ unsigned short f2bf(float f) {
  unsigned u = __float_as_uint(f);
  u += 0x7fffu + ((u >> 16) & 1u);   // RNE
  return (unsigned short)(u >> 16);
}

// ---------------- fp32 -> bf16 conversion (memory-bound, vectorized) ----------------
__global__ void cvt_kernel(const float* __restrict__ src, unsigned short* __restrict__ dst, int n4) {
  int stride = gridDim.x * blockDim.x;
  for (int i = blockIdx.x * blockDim.x + threadIdx.x; i < n4; i += stride) {
    float4 v = reinterpret_cast<const float4*>(src)[i];
    ushort4 o;
    o.x = f2bf(v.x); o.y = f2bf(v.y); o.z = f2bf(v.z); o.w = f2bf(v.w);
    reinterpret_cast<ushort4*>(dst)[i] = o;
  }
}

// ---------------- router: logits, softmax, top-2; NO contended atomics ----------------
// one wave per token (4 waves/block); per-block psum partials via LDS -> plain store
__global__ void router_kernel(const float* __restrict__ x, const float* __restrict__ Wr,
                              float* __restrict__ partials, unsigned char* __restrict__ topidx,
                              float* __restrict__ pslot) {
  __shared__ float sp[NE];
  int lane = threadIdx.x & 63;
  int wv = threadIdx.x >> 6;
  int token = blockIdx.x * 4 + wv;
  if (threadIdx.x < NE) sp[threadIdx.x] = 0.f;
  __syncthreads();

  const float4* xr = (const float4*)(x + (size_t)token * DM);
  float acc[NE];
#pragma unroll
  for (int e = 0; e < NE; e++) acc[e] = 0.f;
#pragma unroll
  for (int d = lane; d < DM / 4; d += 64) {
    float4 xv = xr[d];
#pragma unroll
    for (int e = 0; e < NE; e++) {
      float4 wv4 = ((const float4*)(Wr + e * DM))[d];
      acc[e] += xv.x * wv4.x + xv.y * wv4.y + xv.z * wv4.z + xv.w * wv4.w;
    }
  }
#pragma unroll
  for (int e = 0; e < NE; e++) {
#pragma unroll
    for (int off = 32; off > 0; off >>= 1) acc[e] += __shfl_xor(acc[e], off);
  }
  if (lane == 0) {
    float m = acc[0];
#pragma unroll
    for (int e = 1; e < NE; e++) m = fmaxf(m, acc[e]);
    float p[NE];
    float s = 0.f;
#pragma unroll
    for (int e = 0; e < NE; e++) { p[e] = expf(acc[e] - m); s += p[e]; }
    float inv = 1.f / s;
#pragma unroll
    for (int e = 0; e < NE; e++) p[e] *= inv;
    // top-2, earliest index wins ties (jax top_k semantics)
    int i1 = 0;
#pragma unroll
    for (int e = 1; e < NE; e++) if (p[e] > p[i1]) i1 = e;
    int i2 = (i1 == 0) ? 1 : 0;
#pragma unroll
    for (int e = 0; e < NE; e++) if (e != i1 && p[e] > p[i2]) i2 = e;
    float denom = p[i1] + p[i2] + 1e-8f;
    topidx[token] = (unsigned char)(i1 | (i2 << 4));
    pslot[2 * token]     = p[i1] / denom;
    pslot[2 * token + 1] = p[i2] / denom;
#pragma unroll
    for (int e = 0; e < NE; e++) atomicAdd(&sp[e], p[e]);  // LDS atomic, 4 waves only
  }
  __syncthreads();
  if (threadIdx.x < NE) partials[blockIdx.x * NE + threadIdx.x] = sp[threadIdx.x];
}

// ---------------- scatter: wave-aggregated position assignment ----------------
__global__ void scatter_kernel(const unsigned char* __restrict__ topidx,
                               int* __restrict__ counts, int* __restrict__ lists) {
  int token = blockIdx.x * blockDim.x + threadIdx.x;
  int lane = threadIdx.x & 63;
  unsigned char packed = topidx[token];
#pragma unroll
  for (int c = 0; c < 2; c++) {
    int myexp = (c == 0) ? (packed & 15) : (packed >> 4);
    int slot = 2 * token + c;
#pragma unroll
    for (int e = 0; e < NE; e++) {
      unsigned long long mask = __ballot(myexp == e);
      int cnt = __popcll(mask);
      if (cnt) {
        int base = 0;
        if (lane == 0) base = atomicAdd(&counts[e], cnt);
        base = __shfl(base, 0);
        if (myexp == e) {
          int mypos = base + __popcll(mask & ((1ull << lane) - 1ull));
          lists[e * N_TOK + mypos] = slot;
        }
      }
    }
  }
}

// ---------------- aux loss: reduce per-block psum partials ----------------
__global__ void aux_kernel(const float* __restrict__ partials, int nblk,
                           float* __restrict__ aux_out) {
  __shared__ float sp[NE];
  if (threadIdx.x < NE) sp[threadIdx.x] = 0.f;
  __syncthreads();
  float s = 0.f;
  for (int i = threadIdx.x; i < nblk * NE; i += 256) s += partials[i];  // stride 256 keeps e = tid&7
  atomicAdd(&sp[threadIdx.x & 7], s);
  __syncthreads();
  if (threadIdx.x == 0) {
    float a = 0.f;
#pragma unroll
    for (int e = 0; e < NE; e++) {
      float tpe = sp[e] * (1.0f / N_TOK);
      float d = tpe - 1.0f / NE;
      a += d * d;
    }
    aux_out[0] = 0.01f * (a * (1.0f / NE));
  }
}

// ---------------- grouped GEMM: C = gather(A) * B^T, 128x128 tile, BK=64 ----------------
template <int KDIM, bool IS_GEMM1>
__global__ __launch_bounds__(256) void moe_gemm(
    const unsigned short* __restrict__ Aglob,
    const unsigned short* __restrict__ Bglob,
    const int* __restrict__ counts,
    const int* __restrict__ lists,
    const float* __restrict__ pslot,
    unsigned short* __restrict__ hb,
    float* __restrict__ out) {
  int e = blockIdx.z, mt = blockIdx.y, nt = blockIdx.x;
  int cnt = counts[e];
  if (mt * 128 >= cnt) return;
  const int* list = lists + e * N_TOK;
  int Ncols = gridDim.x * 128;
  const unsigned short* B = Bglob + (size_t)e * Ncols * KDIM;

  __shared__ unsigned short As[128 * 64];
  __shared__ unsigned short Bs[128 * 64];

  int tid = threadIdx.x;
  int wid = tid >> 6;
  int lane = tid & 63;
  int wr = wid >> 1, wc = wid & 1;  // 2x2 waves, each 64x64 output

  int acol = (lane & 7) * 8;  // bf16 col offset within BK=64
  const unsigned short* asrc[4];
  const unsigned short* bsrc[4];
#pragma unroll
  for (int i = 0; i < 4; i++) {
    int c = i * 4 + wid;
    int r = c * 8 + (lane >> 3);  // tile row 0..127
    int p = mt * 128 + r;
    int pc = p < cnt ? p : cnt - 1;
    int slot = list[pc];
    int arow = IS_GEMM1 ? (slot >> 1) : slot;
    asrc[i] = Aglob + (size_t)arow * KDIM + acol;
    bsrc[i] = B + (size_t)(nt * 128 + r) * KDIM + acol;
  }

  f32x4 acc[4][4];
#pragma unroll
  for (int m = 0; m < 4; m++)
#pragma unroll
    for (int n = 0; n < 4; n++) acc[m][n] = (f32x4){0.f, 0.f, 0.f, 0.f};

  for (int kk = 0; kk < KDIM; kk += 64) {
    if (kk > 0) __syncthreads();
#pragma unroll
    for (int i = 0; i < 4; i++) {
      int c = i * 4 + wid;
      __builtin_amdgcn_global_load_lds((const void*)(asrc[i] + kk), (void*)(&As[c * 512]), 16, 0, 0);
      __builtin_amdgcn_global_load_lds((const void*)(bsrc[i] + kk), (void*)(&Bs[c * 512]), 16, 0, 0);
    }
    asm volatile("s_waitcnt vmcnt(0)" ::: "memory");
    __syncthreads();
#pragma unroll
    for (int ks = 0; ks < 2; ks++) {
      short8 a[4], b[4];
#pragma unroll
      for (int m = 0; m < 4; m++)
        a[m] = *reinterpret_cast<const short8*>(&As[(wr * 64 + m * 16 + (lane & 15)) * 64 + ks * 32 + (lane >> 4) * 8]);
#pragma unroll
      for (int n = 0; n < 4; n++)
        b[n] = *reinterpret_cast<const short8*>(&Bs[(wc * 64 + n * 16 + (lane & 15)) * 64 + ks * 32 + (lane >> 4) * 8]);
#pragma unroll
      for (int m = 0; m < 4; m++)
#pragma unroll
        for (int n = 0; n < 4; n++)
          acc[m][n] = __builtin_amdgcn_mfma_f32_16x16x32_bf16(a[m], b[n], acc[m][n], 0, 0, 0);
    }
  }

  int colbase = nt * 128 + wc * 64 + (lane & 15);
#pragma unroll
  for (int m = 0; m < 4; m++) {
#pragma unroll
    for (int r = 0; r < 4; r++) {
      int row_local = wr * 64 + m * 16 + (lane >> 4) * 4 + r;
      int p = mt * 128 + row_local;
      if (p < cnt) {
        int slot = list[p];
        if (IS_GEMM1) {
          size_t base = (size_t)slot * FH + colbase;
#pragma unroll
          for (int n = 0; n < 4; n++) {
            float v = acc[m][n][r];
            float g = 0.5f * v * (1.f + erff(v * 0.70710678118654752f));
            hb[base + n * 16] = f2bf(g);
          }
        } else {
          float sc = pslot[slot];
          int token = slot >> 1;
          size_t base = (size_t)token * DM + colbase;
#pragma unroll
          for (int n = 0; n < 4; n++) atomicAdd(&out[base + n * 16], sc * acc[m][n][r]);
        }
      }
    }
  }
}

extern "C" void kernel_launch(void* const* d_in, const int* in_sizes, int n_in,
                              void* d_out, int out_size, void* d_ws, size_t ws_size,
                              hipStream_t stream) {
  const float* x  = (const float*)d_in[0];
  const float* Wr = (const float*)d_in[1];
  const float* W1 = (const float*)d_in[2];
  const float* W2 = (const float*)d_in[3];
  float* out = (float*)d_out;

  char* ws = (char*)d_ws;
  int*   counts   = (int*)(ws + 0);                         // 32 B
  unsigned char* topidx = (unsigned char*)(ws + 64);        // 4096 B
  float* pslot    = (float*)(ws + 8192);                    // 32768 B
  float* partials = (float*)(ws + 40960);                   // 1024*8*4 = 32768 B
  int*   lists    = (int*)(ws + 73728);                     // 131072 B -> ends 204800
  unsigned short* xb  = (unsigned short*)(ws + 204800);                  // 8 MiB
  unsigned short* w1b = (unsigned short*)(ws + 204800 + 8388608);        // 64 MiB
  unsigned short* w2b = (unsigned short*)(ws + 204800 + 8388608 + 67108864);
  unsigned short* hb  = (unsigned short*)(ws + 204800 + 8388608 + 2 * 67108864);
  (void)in_sizes; (void)n_in; (void)ws_size;

  hipMemsetAsync(counts, 0, 64, stream);
  hipMemsetAsync(d_out, 0, (size_t)out_size * sizeof(float), stream);

  cvt_kernel<<<2048, 256, 0, stream>>>(x,  xb,  N_TOK * DM / 4);
  cvt_kernel<<<2048, 256, 0, stream>>>(W1, w1b, NE * FH * DM / 4);
  cvt_kernel<<<2048, 256, 0, stream>>>(W2, w2b, NE * DM * FH / 4);

  router_kernel<<<N_TOK / 4, 256, 0, stream>>>(x, Wr, partials, topidx, pslot);
  scatter_kernel<<<N_TOK / 256, 256, 0, stream>>>(topidx, counts, lists);
  aux_kernel<<<1, 256, 0, stream>>>(partials, N_TOK / 4, out + (size_t)N_TOK * DM);

  // GEMM1: M<=cnt, N=FH(4096), K=DM(1024)
  moe_gemm<DM, true><<<dim3(FH / 128, N_TOK / 128, NE), 256, 0, stream>>>(
      xb, w1b, counts, lists, pslot, hb, nullptr);
  // GEMM2: M<=cnt, N=DM(1024), K=FH(4096)
  moe_gemm<FH, false><<<dim3(DM / 128, N_TOK / 128, NE), 256, 0, stream>>>(
      hb, w2b, counts, lists, pslot, nullptr, out);
}